// Round 14
// baseline (219.822 us; speedup 1.0000x reference)
//
#include <hip/hip_runtime.h>
#include <hip/hip_bf16.h>

#define B_ 16
#define N_ 4096
#define S_ 1024
#define K_ 32
#define D_ 64
#define M_ (B_*S_*K_)            // 524288 gathered rows (with duplicates)
#define U_ (B_*N_)               // 65536 unique point rows
#define EPS_ 1e-5f

#define OUT_NRM  (B_*S_*3)       // 49152
#define OUT_FEAT (2*B_*S_*3)     // 98304
#define OUT_FPS  (OUT_FEAT + B_*S_*128)  // 2195456

typedef __attribute__((ext_vector_type(8))) short bf16x8;
typedef __attribute__((ext_vector_type(4))) float f32x4;
typedef unsigned long long u64;

__device__ __forceinline__ unsigned short rnb(float x){
  return (unsigned short)((__float_as_uint(x) + 0x8000u) >> 16);
}
__device__ __forceinline__ void split1(float x, short& h, short& l){
  unsigned ux = __float_as_uint(x);
  unsigned uh = (ux + 0x8000u) & 0xFFFF0000u;
  h = (short)(uh >> 16);
  float lo = x - __uint_as_float(uh);
  l = (short)((__float_as_uint(lo) + 0x8000u) >> 16);
}
__device__ __forceinline__ unsigned f2key(float d){
  unsigned u = __float_as_uint(d);
  return u ^ ((unsigned)(((int)u) >> 31) | 0x80000000u);
}
__device__ __forceinline__ unsigned mprefix(u64 m){
  return __builtin_amdgcn_mbcnt_hi((unsigned)(m >> 32),
         __builtin_amdgcn_mbcnt_lo((unsigned)m, 0u));
}

// reduce 4 values across 16 lr-lanes; lane with bits(3,2)=(b3,b2) holds total of v[2*b3+b2]
__device__ __forceinline__ float hred4_sum(const float v[4], int l){
  bool hi8 = (l & 8) != 0;
  float send0 = hi8 ? v[0] : v[2];
  float send1 = hi8 ? v[1] : v[3];
  float r0 = __shfl_xor(send0, 8);
  float r1 = __shfl_xor(send1, 8);
  float a0 = (hi8 ? v[2] : v[0]) + r0;
  float a1 = (hi8 ? v[3] : v[1]) + r1;
  bool hi4 = (l & 4) != 0;
  float send = hi4 ? a0 : a1;
  float r = __shfl_xor(send, 4);
  float a = (hi4 ? a1 : a0) + r;
  a += __shfl_xor(a, 2);
  a += __shfl_xor(a, 1);
  return a;
}

// ---- 64-lane bitonic sorts (ascending across lanes), dual-query interleaved ----
__device__ __forceinline__ void bsort64_f32x2(float& v0, float& v1, int l){
  #pragma unroll
  for (int k = 2; k <= 64; k <<= 1){
    #pragma unroll
    for (int j = k >> 1; j > 0; j >>= 1){
      bool keepmn = (((l & k) == 0) == ((l & j) == 0));
      float o0 = __shfl_xor(v0, j);
      float o1 = __shfl_xor(v1, j);
      v0 = keepmn ? fminf(v0, o0) : fmaxf(v0, o0);
      v1 = keepmn ? fminf(v1, o1) : fmaxf(v1, o1);
    }
  }
}
__device__ __forceinline__ void bsort64_u64x2(u64& v0, u64& v1, int l){
  #pragma unroll
  for (int k = 2; k <= 64; k <<= 1){
    #pragma unroll
    for (int j = k >> 1; j > 0; j >>= 1){
      bool keepmn = (((l & k) == 0) == ((l & j) == 0));
      u64 o0 = __shfl_xor((unsigned long long)v0, j);
      u64 o1 = __shfl_xor((unsigned long long)v1, j);
      bool a0 = v0 < o0, a1 = v1 < o1;
      v0 = (a0 == keepmn) ? v0 : o0;
      v1 = (a1 == keepmn) ? v1 : o1;
    }
  }
}

// ---- prep: packxyz + meta + packw + zero stats/mult fused ----
__global__ void prep_kernel(const float* __restrict__ xyz, const float* __restrict__ nrm,
                            const int* __restrict__ fps,
                            const float* __restrict__ w0, const float* __restrict__ w1,
                            const float* __restrict__ w2,
                            float* __restrict__ out, float4* __restrict__ px,
                            unsigned short* __restrict__ wdst, float* __restrict__ stats,
                            unsigned* __restrict__ mult){
  const int bid = blockIdx.x, tid = threadIdx.x;
  if (bid < 256){
    int t = bid*256 + tid;
    const float* p = xyz + (size_t)t*3;
    float x = p[0], y = p[1], z = p[2];
    float pp = __fadd_rn(__fadd_rn(__fmul_rn(x,x), __fmul_rn(y,y)), __fmul_rn(z,z));
    px[t] = make_float4(__fmul_rn(-2.f,x), __fmul_rn(-2.f,y), __fmul_rn(-2.f,z), pp);
  } else if (bid < 320){
    // meta
    int t = (bid-256)*256 + tid;
    int b = t >> 10;
    int n = fps[t];
    const float* xp = xyz + ((size_t)b*N_ + n)*3;
    out[t*3+0] = xp[0]; out[t*3+1] = xp[1]; out[t*3+2] = xp[2];
    const float* pp = nrm + ((size_t)b*N_ + n)*3;
    out[OUT_NRM + t*3+0] = pp[0]; out[OUT_NRM + t*3+1] = pp[1]; out[OUT_NRM + t*3+2] = pp[2];
    out[OUT_FPS + t] = (float)n;
  } else if (bid < 384){
    // packw
    int e = (bid-320)*256 + tid;
    const float* W; int base;
    if (e < 4096){ W = w0; base = 0; }
    else if (e < 8192){ W = w1; base = 4096; }
    else { W = w2; base = 8192; }
    int r = e - base;
    int frag = r >> 9;
    int lane = (r >> 3) & 63;
    int j = r & 7;
    int cht = frag >> 1, ks = frag & 1;
    int m = lane & 15, quad = lane >> 4;
    int ch = cht*16 + m, k = ks*32 + quad*8 + j;
    wdst[e] = rnb(W[ch*64 + k]);
  } else if (bid < 400){
    stats[(bid-384)*256 + tid] = 0.f;
  } else {
    mult[(bid-400)*256 + tid] = 0u;    // 256 blocks cover 65536
  }
}

// approximate screen distance: 4 ops (1 add + 3 fma); |err| <= ~1.2e-4
#define DISTA(P,QX,QY,QZ,QQ) __builtin_fmaf((P).x,(QX), \
  __builtin_fmaf((P).y,(QY), __builtin_fmaf((P).z,(QZ), (P).w + (QQ))))

// exact legacy distance from packed (-2x,-2y,-2z,pp) — bit-identical to all passing rounds
__device__ __forceinline__ float dist_exact(float4 P, float qx, float qy, float qz, float qq){
  float px = -0.5f*P.x, py = -0.5f*P.y, pz = -0.5f*P.z;   // exact recovery
  float dt = __fadd_rn(__fadd_rn(__fmul_rn(qx,px), __fmul_rn(qy,py)), __fmul_rn(qz,pz));
  return __fsub_rn(__fadd_rn(qq,P.w), __fmul_rn(2.f,dt));
}

#define MARGIN_ 1e-3f

// proven fallback (rare): exact selection over up to 128 candidates via 44-bit search
__device__ __forceinline__ void sel_fallback(const u64* sp, unsigned tot, int l,
                                             int* __restrict__ outp){
  if (tot <= 64){
    u64 pair = sp[l];
    u64 plo = 0, phi = (1ull << 44) - 1;
    for (int it = 0; it < 44; ++it){
      u64 mid = plo + ((phi - plo) >> 1);
      u64 m = __ballot(pair <= mid);
      if (__popcll(m) >= 32) phi = mid; else plo = mid + 1;
    }
    bool sel = (pair <= plo);
    u64 m = __ballot(sel);
    unsigned pos = mprefix(m);
    if (sel) outp[pos] = (int)(pair & 0xFFFull);
  } else {
    u64 pa = sp[l], pb = sp[64 + l];
    u64 plo = 0, phi = (1ull << 44) - 1;
    for (int it = 0; it < 44; ++it){
      u64 mid = plo + ((phi - plo) >> 1);
      int c = __popcll(__ballot(pa <= mid)) + __popcll(__ballot(pb <= mid));
      if (c >= 32) phi = mid; else plo = mid + 1;
    }
    int ca = (pa <= plo) ? 1 : 0;
    int cb = (pb <= plo) ? 1 : 0;
    int c2 = ca + cb, inc = c2;
    #pragma unroll
    for (int off = 1; off < 64; off <<= 1){
      int tv = __shfl_up(inc, off);
      if (l >= off) inc += tv;
    }
    int pos = inc - c2;
    if (ca){ outp[pos] = (int)(pa & 0xFFFull); pos++; }
    if (cb){ outp[pos] = (int)(pb & 0xFFFull); }
  }
}

// ---- KNN pass 1 (probe split, proven in R10): screen + bitonic threshold -> Tm.
// Tm round-trips through global bit-exactly -> outputs identical ----
__global__ __launch_bounds__(256, 8) void knn_pass1(const float4* __restrict__ pxyz,
                                                    const int* __restrict__ fps,
                                                    float* __restrict__ Tm){
  const int t = threadIdx.x, w = t >> 6, l = t & 63;
  const int b = blockIdx.x >> 7;
  const float4* __restrict__ Pp = pxyz + (size_t)b*N_;
  const int q0 = blockIdx.x*8 + w*2;
  const int nq0 = fps[q0], nq1 = fps[q0+1];
  const float4 Q0 = Pp[nq0], Q1 = Pp[nq1];
  const float qx0 = -0.5f*Q0.x, qy0 = -0.5f*Q0.y, qz0 = -0.5f*Q0.z, qq0 = Q0.w;
  const float qx1 = -0.5f*Q1.x, qy1 = -0.5f*Q1.y, qz1 = -0.5f*Q1.z, qq1 = Q1.w;

  float vmin0 = 3.0e38f, vmin1 = 3.0e38f;
  #pragma unroll 8
  for (int i = 0; i < 64; i++){
    float4 P = Pp[i*64 + l];
    float d0 = DISTA(P, qx0, qy0, qz0, qq0); vmin0 = fminf(vmin0, d0);
    float d1 = DISTA(P, qx1, qy1, qz1, qq1); vmin1 = fminf(vmin1, d1);
  }
  float s0 = vmin0, s1 = vmin1;
  bsort64_f32x2(s0, s1, l);
  if (l == 31){
    Tm[q0]     = s0 + MARGIN_;
    Tm[q0 + 1] = s1 + MARGIN_;
  }
}

// ---- KNN pass 2: margin-guarded re-screen + exact keys + bitonic selection ----
__global__ __launch_bounds__(256, 8) void knn_pass2(const float4* __restrict__ pxyz,
                                                    const int* __restrict__ fps,
                                                    const float* __restrict__ Tm,
                                                    int* __restrict__ idxout){
  __shared__ u64 spair[4][2][128];
  const int t = threadIdx.x, w = t >> 6, l = t & 63;
  const int b = blockIdx.x >> 7;
  const float4* __restrict__ Pp = pxyz + (size_t)b*N_;
  const int q0 = blockIdx.x*8 + w*2;
  const int nq0 = fps[q0], nq1 = fps[q0+1];
  const float4 Q0 = Pp[nq0], Q1 = Pp[nq1];
  const float qx0 = -0.5f*Q0.x, qy0 = -0.5f*Q0.y, qz0 = -0.5f*Q0.z, qq0 = Q0.w;
  const float qx1 = -0.5f*Q1.x, qy1 = -0.5f*Q1.y, qz1 = -0.5f*Q1.z, qq1 = Q1.w;
  const float Tm0 = Tm[q0], Tm1 = Tm[q0 + 1];

  spair[w][0][l] = ~0ull; spair[w][0][64 + l] = ~0ull;
  spair[w][1][l] = ~0ull; spair[w][1][64 + l] = ~0ull;

  unsigned cnt0 = 0, cnt1 = 0;
  #pragma unroll 4
  for (int i = 0; i < 64; i++){
    unsigned n = (unsigned)(i*64 + l);
    float4 P = Pp[n];
    {
      float da = DISTA(P, qx0, qy0, qz0, qq0);
      bool c = (da <= Tm0);
      u64 m = __ballot(c);
      if (c){
        float de = dist_exact(P, qx0, qy0, qz0, qq0);
        unsigned pos = cnt0 + mprefix(m);
        if (pos < 128) spair[w][0][pos] = ((u64)f2key(de) << 12) | n;
      }
      cnt0 += (unsigned)__popcll(m);
    }
    {
      float da = DISTA(P, qx1, qy1, qz1, qq1);
      bool c = (da <= Tm1);
      u64 m = __ballot(c);
      if (c){
        float de = dist_exact(P, qx1, qy1, qz1, qq1);
        unsigned pos = cnt1 + mprefix(m);
        if (pos < 128) spair[w][1][pos] = ((u64)f2key(de) << 12) | n;
      }
      cnt1 += (unsigned)__popcll(m);
    }
  }

  const size_t obase = (size_t)q0 * K_;
  if (cnt0 <= 64 && cnt1 <= 64){
    u64 P0 = spair[w][0][l], P1 = spair[w][1][l];
    bsort64_u64x2(P0, P1, l);
    if (l < 32){
      idxout[obase + l]      = (int)(P0 & 0xFFFull);
      idxout[obase + K_ + l] = (int)(P1 & 0xFFFull);
    }
  } else {
    sel_fallback(&spair[w][0][0], cnt0, l, idxout + obase);
    sel_fallback(&spair[w][1][0], cnt1, l, idxout + obase + K_);
  }
}

// ---- hist: multiplicity of each unique point in the gathered tensor ----
__global__ void hist_kernel(const int* __restrict__ idx, unsigned* __restrict__ mult){
  int i = blockIdx.x*256 + threadIdx.x;    // 524288 entries
  int b = i >> 15;                          // 32768 per batch
  atomicAdd(&mult[b*4096 + idx[i]], 1u);
}

// ---- conv1u (R23 proven): 65536 unique rows, coalesced pts read, weighted stats ----
__global__ __launch_bounds__(256, 4) void conv1_mfma(const float* __restrict__ pts,
    const unsigned* __restrict__ mult, const unsigned short* __restrict__ wpk,
    const float* __restrict__ bias, unsigned short* __restrict__ Yo,
    float* __restrict__ stats){
  __shared__ float sred[4][128];
  __shared__ uint4 Wl4[512];
  const unsigned short* Wl = (const unsigned short*)Wl4;
  const int t = threadIdx.x, w = t>>6, l = t&63, quad = l>>4, lr = l&15;
  const int Rw = blockIdx.x*128 + w*32;
  Wl4[t] = ((const uint4*)wpk)[t];
  Wl4[256 + t] = ((const uint4*)wpk)[256 + t];
  f32x4 acc[4][2];
  #pragma unroll
  for (int c = 0; c < 4; c++)
    #pragma unroll
    for (int rt = 0; rt < 2; rt++)
      acc[c][rt] = (f32x4){0.f,0.f,0.f,0.f};
  float mf[2];
  mf[0] = (float)mult[Rw + lr];
  mf[1] = (float)mult[Rw + 16 + lr];
  __syncthreads();
  #pragma unroll
  for (int s = 0; s < 2; s++){
    bf16x8 wfs[4];
    #pragma unroll
    for (int c = 0; c < 4; c++)
      wfs[c] = *(const bf16x8*)(Wl + (((c*2+s)<<6) + l)*8);
    #pragma unroll
    for (int rt = 0; rt < 2; rt++){
      const float* pr = pts + (size_t)(Rw + rt*16 + lr)*64;
      float4 v0 = *(const float4*)(pr + s*32 + quad*8);
      float4 v1 = *(const float4*)(pr + s*32 + quad*8 + 4);
      float xs[8] = {v0.x,v0.y,v0.z,v0.w,v1.x,v1.y,v1.z,v1.w};
      bf16x8 xh, xl;
      #pragma unroll
      for (int j = 0; j < 8; j++){ short hh, ll; split1(xs[j], hh, ll); xh[j]=hh; xl[j]=ll; }
      #pragma unroll
      for (int c = 0; c < 4; c++){
        acc[c][rt] = __builtin_amdgcn_mfma_f32_16x16x32_bf16(wfs[c], xh, acc[c][rt], 0,0,0);
        acc[c][rt] = __builtin_amdgcn_mfma_f32_16x16x32_bf16(wfs[c], xl, acc[c][rt], 0,0,0);
      }
    }
  }
  const int rtg0 = Rw >> 4;
  #pragma unroll
  for (int c = 0; c < 4; c++){
    float4 bq = *(const float4*)(bias + c*16 + quad*4);
    float bqa[4] = {bq.x, bq.y, bq.z, bq.w};
    float sv[4] = {0,0,0,0}, qv[4] = {0,0,0,0};
    int kb = c*2 + (quad>>1);
    int sub = (quad&1)*4;
    #pragma unroll
    for (int rt = 0; rt < 2; rt++){
      float y[4];
      #pragma unroll
      for (int r = 0; r < 4; r++){
        y[r] = acc[c][rt][r] + bqa[r];
        sv[r] += mf[rt]*y[r];
        qv[r] += mf[rt]*y[r]*y[r];
      }
      uint2 p;
      p.x = (unsigned)rnb(y[0]) | ((unsigned)rnb(y[1])<<16);
      p.y = (unsigned)rnb(y[2]) | ((unsigned)rnb(y[3])<<16);
      *(uint2*)(Yo + ((((rtg0+rt)*8 + kb)*16 + lr)*8 + sub)) = p;
    }
    float S = hred4_sum(sv, l);
    float Q = hred4_sum(qv, l);
    if ((l & 3) == 0){
      int ch = c*16 + quad*4 + ((l>>3)&1)*2 + ((l>>2)&1);
      sred[w][ch] = S;
      sred[w][64 + ch] = Q;
    }
  }
  __syncthreads();
  if (t < 128){
    float tot = sred[0][t]+sred[1][t]+sred[2][t]+sred[3][t];
    unsafeAtomicAdd(&stats[(blockIdx.x & 7)*512 + t], tot);
  }
}

// ---- conv2u (R23 proven): 65536 unique rows, weighted stats ----
__global__ __launch_bounds__(256, 4) void conv2_mfma(const unsigned short* __restrict__ Yi,
    const unsigned* __restrict__ mult, const unsigned short* __restrict__ wpk,
    const float* __restrict__ bias, const float* __restrict__ gg,
    const float* __restrict__ btv, unsigned short* __restrict__ Yo,
    float* __restrict__ stats){
  __shared__ float sred[4][128];
  __shared__ float sAff[128];
  __shared__ uint4 Wl4[512];
  const unsigned short* Wl = (const unsigned short*)Wl4;
  const int t = threadIdx.x, w = t>>6, l = t&63, quad = l>>4, lr = l&15;
  const int Rw = blockIdx.x*128 + w*32;
  Wl4[t] = ((const uint4*)wpk)[t];
  Wl4[256 + t] = ((const uint4*)wpk)[256 + t];
  if (t < 64){
    const float inv = 1.f/(float)M_;
    float S = 0.f, Q = 0.f;
    #pragma unroll
    for (int r = 0; r < 8; r++){
      S += stats[r*512 + t];
      Q += stats[r*512 + 64 + t];
    }
    float mean = S * inv;
    float var  = Q * inv - mean*mean;
    float a = gg[t] * rsqrtf(var + EPS_);
    sAff[t] = a;
    sAff[64 + t] = btv[t] - mean*a;
  }
  f32x4 acc[4][2];
  #pragma unroll
  for (int c = 0; c < 4; c++)
    #pragma unroll
    for (int rt = 0; rt < 2; rt++)
      acc[c][rt] = (f32x4){0.f,0.f,0.f,0.f};
  float mf[2];
  mf[0] = (float)mult[Rw + lr];
  mf[1] = (float)mult[Rw + 16 + lr];
  const int rtg0 = Rw >> 4;
  uint4 u[2][2];
  #pragma unroll
  for (int s = 0; s < 2; s++)
    #pragma unroll
    for (int rt = 0; rt < 2; rt++)
      u[s][rt] = *(const uint4*)(Yi + (((rtg0+rt)*8 + s*4 + quad)*16 + lr)*8);
  __syncthreads();
  #pragma unroll
  for (int s = 0; s < 2; s++){
    float4 A0 = *(const float4*)(sAff + s*32 + quad*8);
    float4 A1 = *(const float4*)(sAff + s*32 + quad*8 + 4);
    float4 B0 = *(const float4*)(sAff + 64 + s*32 + quad*8);
    float4 B1 = *(const float4*)(sAff + 64 + s*32 + quad*8 + 4);
    float aA[8] = {A0.x,A0.y,A0.z,A0.w,A1.x,A1.y,A1.z,A1.w};
    float aB[8] = {B0.x,B0.y,B0.z,B0.w,B1.x,B1.y,B1.z,B1.w};
    bf16x8 wfs[4];
    #pragma unroll
    for (int c = 0; c < 4; c++)
      wfs[c] = *(const bf16x8*)(Wl + (((c*2+s)<<6) + l)*8);
    #pragma unroll
    for (int rt = 0; rt < 2; rt++){
      unsigned ua[4] = {u[s][rt].x, u[s][rt].y, u[s][rt].z, u[s][rt].w};
      bf16x8 xb;
      #pragma unroll
      for (int j = 0; j < 8; j++){
        unsigned wd = ua[j>>1];
        float yf = __uint_as_float((j&1) ? (wd & 0xFFFF0000u) : (wd << 16));
        float x = fmaxf(0.f, fmaf(yf, aA[j], aB[j]));
        xb[j] = (short)rnb(x);
      }
      #pragma unroll
      for (int c = 0; c < 4; c++)
        acc[c][rt] = __builtin_amdgcn_mfma_f32_16x16x32_bf16(wfs[c], xb, acc[c][rt], 0,0,0);
    }
  }
  #pragma unroll
  for (int c = 0; c < 4; c++){
    float4 bq = *(const float4*)(bias + c*16 + quad*4);
    float bqa[4] = {bq.x, bq.y, bq.z, bq.w};
    float sv[4] = {0,0,0,0}, qv[4] = {0,0,0,0};
    int kb = c*2 + (quad>>1);
    int sub = (quad&1)*4;
    #pragma unroll
    for (int rt = 0; rt < 2; rt++){
      float y[4];
      #pragma unroll
      for (int r = 0; r < 4; r++){
        y[r] = acc[c][rt][r] + bqa[r];
        sv[r] += mf[rt]*y[r];
        qv[r] += mf[rt]*y[r]*y[r];
      }
      uint2 p;
      p.x = (unsigned)rnb(y[0]) | ((unsigned)rnb(y[1])<<16);
      p.y = (unsigned)rnb(y[2]) | ((unsigned)rnb(y[3])<<16);
      *(uint2*)(Yo + ((((rtg0+rt)*8 + kb)*16 + lr)*8 + sub)) = p;
    }
    float S = hred4_sum(sv, l);
    float Q = hred4_sum(qv, l);
    if ((l & 3) == 0){
      int ch = c*16 + quad*4 + ((l>>3)&1)*2 + ((l>>2)&1);
      sred[w][ch] = S;
      sred[w][64 + ch] = Q;
    }
  }
  __syncthreads();
  if (t < 128){
    float tot = sred[0][t]+sred[1][t]+sred[2][t]+sred[3][t];
    unsafeAtomicAdd(&stats[(blockIdx.x & 7)*512 + 128 + t], tot);
  }
}

// ---- conv3u (R23 proven): 65536 unique rows -> zout + weighted stats ----
__global__ __launch_bounds__(256, 3) void conv3_mfma(const unsigned short* __restrict__ Yi,
    const unsigned* __restrict__ mult, const unsigned short* __restrict__ wpk,
    const float* __restrict__ bias, const float* __restrict__ gg,
    const float* __restrict__ btv, float* __restrict__ zout,
    float* __restrict__ stats){
  __shared__ float sred[4][256];
  __shared__ float sAff[128];
  __shared__ uint4 Wl4[1024];
  const unsigned short* Wl = (const unsigned short*)Wl4;
  const int t = threadIdx.x, w = t>>6, l = t&63, quad = l>>4, lr = l&15;
  const int Rw = blockIdx.x*128 + w*32;
  #pragma unroll
  for (int i = 0; i < 4; i++) Wl4[i*256 + t] = ((const uint4*)wpk)[i*256 + t];
  if (t < 64){
    const float inv = 1.f/(float)M_;
    float S = 0.f, Q = 0.f;
    #pragma unroll
    for (int r = 0; r < 8; r++){
      S += stats[r*512 + 128 + t];
      Q += stats[r*512 + 192 + t];
    }
    float mean = S * inv;
    float var  = Q * inv - mean*mean;
    float a = gg[t] * rsqrtf(var + EPS_);
    sAff[t] = a;
    sAff[64 + t] = btv[t] - mean*a;
  }
  f32x4 acc[8][2];
  #pragma unroll
  for (int c = 0; c < 8; c++){
    acc[c][0] = (f32x4){0.f,0.f,0.f,0.f};
    acc[c][1] = (f32x4){0.f,0.f,0.f,0.f};
  }
  float mf[2];
  mf[0] = (float)mult[Rw + lr];
  mf[1] = (float)mult[Rw + 16 + lr];
  const int rtg0 = Rw >> 4;
  uint4 u[2][2];
  #pragma unroll
  for (int s = 0; s < 2; s++)
    #pragma unroll
    for (int rt = 0; rt < 2; rt++)
      u[s][rt] = *(const uint4*)(Yi + (((rtg0+rt)*8 + s*4 + quad)*16 + lr)*8);
  __syncthreads();
  #pragma unroll
  for (int s = 0; s < 2; s++){
    float4 A0 = *(const float4*)(sAff + s*32 + quad*8);
    float4 A1 = *(const float4*)(sAff + s*32 + quad*8 + 4);
    float4 B0 = *(const float4*)(sAff + 64 + s*32 + quad*8);
    float4 B1 = *(const float4*)(sAff + 64 + s*32 + quad*8 + 4);
    float aA[8] = {A0.x,A0.y,A0.z,A0.w,A1.x,A1.y,A1.z,A1.w};
    float aB[8] = {B0.x,B0.y,B0.z,B0.w,B1.x,B1.y,B1.z,B1.w};
    #pragma unroll
    for (int rt = 0; rt < 2; rt++){
      unsigned ua[4] = {u[s][rt].x, u[s][rt].y, u[s][rt].z, u[s][rt].w};
      bf16x8 xb;
      #pragma unroll
      for (int j = 0; j < 8; j++){
        unsigned wd = ua[j>>1];
        float yf = __uint_as_float((j&1) ? (wd & 0xFFFF0000u) : (wd << 16));
        float x = fmaxf(0.f, fmaf(yf, aA[j], aB[j]));
        xb[j] = (short)rnb(x);
      }
      #pragma unroll
      for (int c = 0; c < 8; c++){
        bf16x8 wfc = *(const bf16x8*)(Wl + (((c*2+s)<<6) + l)*8);
        acc[c][rt] = __builtin_amdgcn_mfma_f32_16x16x32_bf16(wfc, xb, acc[c][rt], 0,0,0);
      }
    }
  }
  #pragma unroll
  for (int c = 0; c < 8; c++){
    float4 bq = *(const float4*)(bias + c*16 + quad*4);
    float bqa[4] = {bq.x, bq.y, bq.z, bq.w};
    float sv[4], qv[4];
    #pragma unroll
    for (int rt = 0; rt < 2; rt++){
      float y[4];
      #pragma unroll
      for (int r = 0; r < 4; r++){
        y[r] = acc[c][rt][r] + bqa[r];
        float wy = mf[rt]*y[r];
        if (rt == 0){ sv[r] = wy; qv[r] = wy*y[r]; }
        else        { sv[r] += wy; qv[r] += wy*y[r]; }
      }
      *(float4*)(zout + (size_t)(Rw + rt*16 + lr)*128 + c*16 + quad*4)
          = make_float4(y[0], y[1], y[2], y[3]);
    }
    float S = hred4_sum(sv, l);
    float Q = hred4_sum(qv, l);
    if ((l & 3) == 0){
      int ch = c*16 + quad*4 + ((l>>3)&1)*2 + ((l>>2)&1);
      sred[w][ch] = S;
      sred[w][128 + ch] = Q;
    }
  }
  __syncthreads();
  {
    float tot = sred[0][t]+sred[1][t]+sred[2][t]+sred[3][t];
    unsafeAtomicAdd(&stats[(blockIdx.x & 7)*512 + 256 + t], tot);
  }
}

// ---- maxpool: per query, max over its 32 neighbors' per-point outputs ----
__global__ __launch_bounds__(256, 8) void maxpool_kernel(const int* __restrict__ idx,
    const float* __restrict__ zout, float* __restrict__ ymax){
  __shared__ int sid[4][32];
  const int t = threadIdx.x, w = t>>6, l = t&63;
  const int q = blockIdx.x*4 + w;
  if (l < 32) sid[w][l] = idx[q*32 + l];
  __syncthreads();
  const float* zb = zout + (size_t)(q >> 10) * 4096 * 128;
  float mx = -3.4e38f, my = -3.4e38f;
  #pragma unroll 8
  for (int s = 0; s < 32; s++){
    const float* zp = zb + (size_t)sid[w][s]*128 + l*2;
    float vx = zp[0], vy = zp[1];
    mx = fmaxf(mx, vx);
    my = fmaxf(my, vy);
  }
  ymax[(size_t)q*128 + l*2]     = mx;
  ymax[(size_t)q*128 + l*2 + 1] = my;
}

// ---- final: affine(in-block from stats) + relu, 8 elems/thread ----
__global__ void final_kernel(const float* __restrict__ ymax,
                             const float* __restrict__ stats,
                             const float* __restrict__ gg, const float* __restrict__ btv,
                             float* __restrict__ out){
  __shared__ float sA[128], sB[128];
  const int tid = threadIdx.x;
  if (tid < 128){
    const float inv = 1.f/(float)M_;
    float S = 0.f, Q = 0.f;
    #pragma unroll
    for (int r = 0; r < 8; r++){
      S += stats[r*512 + 256 + tid];
      Q += stats[r*512 + 384 + tid];
    }
    float mean = S * inv;
    float var  = Q * inv - mean*mean;
    float a = gg[tid] * rsqrtf(var + EPS_);
    sA[tid] = a;
    sB[tid] = btv[tid] - mean*a;
  }
  __syncthreads();
  const size_t base = ((size_t)blockIdx.x*256 + tid)*8;   // 1024 blocks cover 2M elems
  float4 v0 = *(const float4*)(ymax + base);
  float4 v1 = *(const float4*)(ymax + base + 4);
  const int c0 = (int)(base & 127);
  float4 a0 = *(const float4*)(sA + c0);
  float4 a1 = *(const float4*)(sA + c0 + 4);
  float4 b0 = *(const float4*)(sB + c0);
  float4 b1 = *(const float4*)(sB + c0 + 4);
  float4 o0, o1;
  o0.x = fmaxf(0.f, a0.x*v0.x + b0.x); o0.y = fmaxf(0.f, a0.y*v0.y + b0.y);
  o0.z = fmaxf(0.f, a0.z*v0.z + b0.z); o0.w = fmaxf(0.f, a0.w*v0.w + b0.w);
  o1.x = fmaxf(0.f, a1.x*v1.x + b1.x); o1.y = fmaxf(0.f, a1.y*v1.y + b1.y);
  o1.z = fmaxf(0.f, a1.z*v1.z + b1.z); o1.w = fmaxf(0.f, a1.w*v1.w + b1.w);
  *(float4*)(out + OUT_FEAT + base) = o0;
  *(float4*)(out + OUT_FEAT + base + 4) = o1;
}

extern "C" void kernel_launch(void* const* d_in, const int* in_sizes, int n_in,
                              void* d_out, int out_size, void* d_ws, size_t ws_size,
                              hipStream_t stream) {
  const float* xyz = (const float*)d_in[0];
  const float* nrm = (const float*)d_in[1];
  const float* pts = (const float*)d_in[2];
  const int*   fps = (const int*)d_in[3];
  const float* w0  = (const float*)d_in[4];
  const float* b0  = (const float*)d_in[5];
  const float* g0  = (const float*)d_in[6];
  const float* bt0 = (const float*)d_in[7];
  const float* w1  = (const float*)d_in[8];
  const float* b1  = (const float*)d_in[9];
  const float* g1  = (const float*)d_in[10];
  const float* bt1 = (const float*)d_in[11];
  const float* w2  = (const float*)d_in[12];
  const float* b2  = (const float*)d_in[13];
  const float* g2  = (const float*)d_in[14];
  const float* bt2 = (const float*)d_in[15];
  float* out = (float*)d_out;

  char* ws = (char*)d_ws;
  float* stats = (float*)ws;                                  // 16 KB
  int*   idxb  = (int*)(ws + 20480);                          // 2 MB
  float* ymax  = (float*)(ws + 2117632);                      // 8 MB
  float4* pxyz = (float4*)(ws + 10506240);                    // 1 MB packed xyz
  unsigned short* wpack = (unsigned short*)(ws + 11554816);   // 32 KB
  unsigned* mult = (unsigned*)(ws + 11620352);                // 256 KB multiplicities
  unsigned short* Y1 = (unsigned short*)(ws + 16777216);      // 8 MB (unique rows)
  unsigned short* Y2 = (unsigned short*)(ws + 33554432);      // 8 MB
  float* zout = (float*)(ws + 50331648);                      // 32 MB per-point f32
  float* Tm   = (float*)(ws + 90000000);                      // 64 KB thresholds

  prep_kernel<<<656, 256, 0, stream>>>(xyz, nrm, fps, w0, w1, w2, out, pxyz, wpack, stats, mult);
  knn_pass1<<<2048, 256, 0, stream>>>(pxyz, fps, Tm);
  knn_pass2<<<2048, 256, 0, stream>>>(pxyz, fps, Tm, idxb);
  hist_kernel<<<2048, 256, 0, stream>>>(idxb, mult);
  conv1_mfma<<<512, 256, 0, stream>>>(pts, mult, wpack, b0, Y1, stats);
  conv2_mfma<<<512, 256, 0, stream>>>(Y1, mult, wpack + 4096, b1, g0, bt0, Y2, stats);
  conv3_mfma<<<512, 256, 0, stream>>>(Y2, mult, wpack + 8192, b2, g1, bt1, zout, stats);
  maxpool_kernel<<<4096, 256, 0, stream>>>(idxb, zout, ymax);
  final_kernel<<<1024, 256, 0, stream>>>(ymax, stats, g2, bt2, out);
}

// Round 15
// 201.298 us; speedup vs baseline: 1.0920x; 1.0920x over previous
//
#include <hip/hip_runtime.h>
#include <hip/hip_bf16.h>

#define B_ 16
#define N_ 4096
#define S_ 1024
#define K_ 32
#define D_ 64
#define M_ (B_*S_*K_)            // 524288 gathered rows (with duplicates)
#define U_ (B_*N_)               // 65536 unique point rows
#define EPS_ 1e-5f

#define OUT_NRM  (B_*S_*3)       // 49152
#define OUT_FEAT (2*B_*S_*3)     // 98304
#define OUT_FPS  (OUT_FEAT + B_*S_*128)  // 2195456

typedef __attribute__((ext_vector_type(8))) short bf16x8;
typedef __attribute__((ext_vector_type(4))) float f32x4;
typedef unsigned long long u64;

__device__ __forceinline__ unsigned short rnb(float x){
  return (unsigned short)((__float_as_uint(x) + 0x8000u) >> 16);
}
__device__ __forceinline__ void split1(float x, short& h, short& l){
  unsigned ux = __float_as_uint(x);
  unsigned uh = (ux + 0x8000u) & 0xFFFF0000u;
  h = (short)(uh >> 16);
  float lo = x - __uint_as_float(uh);
  l = (short)((__float_as_uint(lo) + 0x8000u) >> 16);
}
__device__ __forceinline__ unsigned f2key(float d){
  unsigned u = __float_as_uint(d);
  return u ^ ((unsigned)(((int)u) >> 31) | 0x80000000u);
}
__device__ __forceinline__ unsigned mprefix(u64 m){
  return __builtin_amdgcn_mbcnt_hi((unsigned)(m >> 32),
         __builtin_amdgcn_mbcnt_lo((unsigned)m, 0u));
}

// reduce 4 values across 16 lr-lanes; lane with bits(3,2)=(b3,b2) holds total of v[2*b3+b2]
__device__ __forceinline__ float hred4_sum(const float v[4], int l){
  bool hi8 = (l & 8) != 0;
  float send0 = hi8 ? v[0] : v[2];
  float send1 = hi8 ? v[1] : v[3];
  float r0 = __shfl_xor(send0, 8);
  float r1 = __shfl_xor(send1, 8);
  float a0 = (hi8 ? v[2] : v[0]) + r0;
  float a1 = (hi8 ? v[3] : v[1]) + r1;
  bool hi4 = (l & 4) != 0;
  float send = hi4 ? a0 : a1;
  float r = __shfl_xor(send, 4);
  float a = (hi4 ? a1 : a0) + r;
  a += __shfl_xor(a, 2);
  a += __shfl_xor(a, 1);
  return a;
}

// ---- 64-lane bitonic sorts (ascending across lanes), dual-query interleaved ----
__device__ __forceinline__ void bsort64_f32x2(float& v0, float& v1, int l){
  #pragma unroll
  for (int k = 2; k <= 64; k <<= 1){
    #pragma unroll
    for (int j = k >> 1; j > 0; j >>= 1){
      bool keepmn = (((l & k) == 0) == ((l & j) == 0));
      float o0 = __shfl_xor(v0, j);
      float o1 = __shfl_xor(v1, j);
      v0 = keepmn ? fminf(v0, o0) : fmaxf(v0, o0);
      v1 = keepmn ? fminf(v1, o1) : fmaxf(v1, o1);
    }
  }
}
__device__ __forceinline__ void bsort64_u64x2(u64& v0, u64& v1, int l){
  #pragma unroll
  for (int k = 2; k <= 64; k <<= 1){
    #pragma unroll
    for (int j = k >> 1; j > 0; j >>= 1){
      bool keepmn = (((l & k) == 0) == ((l & j) == 0));
      u64 o0 = __shfl_xor((unsigned long long)v0, j);
      u64 o1 = __shfl_xor((unsigned long long)v1, j);
      bool a0 = v0 < o0, a1 = v1 < o1;
      v0 = (a0 == keepmn) ? v0 : o0;
      v1 = (a1 == keepmn) ? v1 : o1;
    }
  }
}

// ---- prep: packxyz + meta + packw + zero stats/mult fused ----
__global__ void prep_kernel(const float* __restrict__ xyz, const float* __restrict__ nrm,
                            const int* __restrict__ fps,
                            const float* __restrict__ w0, const float* __restrict__ w1,
                            const float* __restrict__ w2,
                            float* __restrict__ out, float4* __restrict__ px,
                            unsigned short* __restrict__ wdst, float* __restrict__ stats,
                            unsigned* __restrict__ mult){
  const int bid = blockIdx.x, tid = threadIdx.x;
  if (bid < 256){
    int t = bid*256 + tid;
    const float* p = xyz + (size_t)t*3;
    float x = p[0], y = p[1], z = p[2];
    float pp = __fadd_rn(__fadd_rn(__fmul_rn(x,x), __fmul_rn(y,y)), __fmul_rn(z,z));
    px[t] = make_float4(__fmul_rn(-2.f,x), __fmul_rn(-2.f,y), __fmul_rn(-2.f,z), pp);
  } else if (bid < 320){
    // meta
    int t = (bid-256)*256 + tid;
    int b = t >> 10;
    int n = fps[t];
    const float* xp = xyz + ((size_t)b*N_ + n)*3;
    out[t*3+0] = xp[0]; out[t*3+1] = xp[1]; out[t*3+2] = xp[2];
    const float* pp = nrm + ((size_t)b*N_ + n)*3;
    out[OUT_NRM + t*3+0] = pp[0]; out[OUT_NRM + t*3+1] = pp[1]; out[OUT_NRM + t*3+2] = pp[2];
    out[OUT_FPS + t] = (float)n;
  } else if (bid < 384){
    // packw
    int e = (bid-320)*256 + tid;
    const float* W; int base;
    if (e < 4096){ W = w0; base = 0; }
    else if (e < 8192){ W = w1; base = 4096; }
    else { W = w2; base = 8192; }
    int r = e - base;
    int frag = r >> 9;
    int lane = (r >> 3) & 63;
    int j = r & 7;
    int cht = frag >> 1, ks = frag & 1;
    int m = lane & 15, quad = lane >> 4;
    int ch = cht*16 + m, k = ks*32 + quad*8 + j;
    wdst[e] = rnb(W[ch*64 + k]);
  } else if (bid < 400){
    stats[(bid-384)*256 + tid] = 0.f;
  } else {
    mult[(bid-400)*256 + tid] = 0u;    // 256 blocks cover 65536
  }
}

// approximate screen distance: 4 ops (1 add + 3 fma); |err| <= ~1.2e-4
#define DISTA(P,QX,QY,QZ,QQ) __builtin_fmaf((P).x,(QX), \
  __builtin_fmaf((P).y,(QY), __builtin_fmaf((P).z,(QZ), (P).w + (QQ))))

// exact legacy distance from packed (-2x,-2y,-2z,pp) — bit-identical to all passing rounds
__device__ __forceinline__ float dist_exact(float4 P, float qx, float qy, float qz, float qq){
  float px = -0.5f*P.x, py = -0.5f*P.y, pz = -0.5f*P.z;   // exact recovery
  float dt = __fadd_rn(__fadd_rn(__fmul_rn(qx,px), __fmul_rn(qy,py)), __fmul_rn(qz,pz));
  return __fsub_rn(__fadd_rn(qq,P.w), __fmul_rn(2.f,dt));
}

#define MARGIN_ 1e-3f

// proven fallback (rare): exact selection over up to 128 candidates via 44-bit search.
// Also bumps the multiplicity histogram for every written index (hist fusion).
__device__ __forceinline__ void sel_fallback(const u64* sp, unsigned tot, int l,
                                             int* __restrict__ outp,
                                             unsigned* __restrict__ multb){
  if (tot <= 64){
    u64 pair = sp[l];
    u64 plo = 0, phi = (1ull << 44) - 1;
    for (int it = 0; it < 44; ++it){
      u64 mid = plo + ((phi - plo) >> 1);
      u64 m = __ballot(pair <= mid);
      if (__popcll(m) >= 32) phi = mid; else plo = mid + 1;
    }
    bool sel = (pair <= plo);
    u64 m = __ballot(sel);
    unsigned pos = mprefix(m);
    if (sel){
      int iv = (int)(pair & 0xFFFull);
      outp[pos] = iv;
      atomicAdd(&multb[iv], 1u);
    }
  } else {
    u64 pa = sp[l], pb = sp[64 + l];
    u64 plo = 0, phi = (1ull << 44) - 1;
    for (int it = 0; it < 44; ++it){
      u64 mid = plo + ((phi - plo) >> 1);
      int c = __popcll(__ballot(pa <= mid)) + __popcll(__ballot(pb <= mid));
      if (c >= 32) phi = mid; else plo = mid + 1;
    }
    int ca = (pa <= plo) ? 1 : 0;
    int cb = (pb <= plo) ? 1 : 0;
    int c2 = ca + cb, inc = c2;
    #pragma unroll
    for (int off = 1; off < 64; off <<= 1){
      int tv = __shfl_up(inc, off);
      if (l >= off) inc += tv;
    }
    int pos = inc - c2;
    if (ca){
      int iv = (int)(pa & 0xFFFull);
      outp[pos] = iv;
      atomicAdd(&multb[iv], 1u);
      pos++;
    }
    if (cb){
      int iv = (int)(pb & 0xFFFull);
      outp[pos] = iv;
      atomicAdd(&multb[iv], 1u);
    }
  }
}

// ---- KNN (R19 proven, re-merged) + fused multiplicity histogram ----
__global__ __launch_bounds__(256, 8) void knn_kernel(const float4* __restrict__ pxyz,
                                                     const int* __restrict__ fps,
                                                     int* __restrict__ idxout,
                                                     unsigned* __restrict__ mult){
  __shared__ u64 spair[4][2][128];
  const int t = threadIdx.x, w = t >> 6, l = t & 63;
  const int b = blockIdx.x >> 7;
  const float4* __restrict__ Pp = pxyz + (size_t)b*N_;
  unsigned* __restrict__ multb = mult + (size_t)b*N_;
  const int q0 = blockIdx.x*8 + w*2;
  const int nq0 = fps[q0], nq1 = fps[q0+1];
  const float4 Q0 = Pp[nq0], Q1 = Pp[nq1];
  const float qx0 = -0.5f*Q0.x, qy0 = -0.5f*Q0.y, qz0 = -0.5f*Q0.z, qq0 = Q0.w;
  const float qx1 = -0.5f*Q1.x, qy1 = -0.5f*Q1.y, qz1 = -0.5f*Q1.z, qq1 = Q1.w;

  // pass 1: per-lane min of APPROX distances
  float vmin0 = 3.0e38f, vmin1 = 3.0e38f;
  #pragma unroll 8
  for (int i = 0; i < 64; i++){
    float4 P = Pp[i*64 + l];
    float d0 = DISTA(P, qx0, qy0, qz0, qq0); vmin0 = fminf(vmin0, d0);
    float d1 = DISTA(P, qx1, qy1, qz1, qq1); vmin1 = fminf(vmin1, d1);
  }

  // threshold: bitonic sort; lane 31 = exact 32nd smallest
  float s0 = vmin0, s1 = vmin1;
  bsort64_f32x2(s0, s1, l);
  const float Tm0 = __shfl(s0, 31) + MARGIN_;
  const float Tm1 = __shfl(s1, 31) + MARGIN_;

  spair[w][0][l] = ~0ull; spair[w][0][64 + l] = ~0ull;
  spair[w][1][l] = ~0ull; spair[w][1][64 + l] = ~0ull;

  // pass 2: approx screen; EXACT legacy key inside the push branch only
  unsigned cnt0 = 0, cnt1 = 0;
  #pragma unroll 4
  for (int i = 0; i < 64; i++){
    unsigned n = (unsigned)(i*64 + l);
    float4 P = Pp[n];
    {
      float da = DISTA(P, qx0, qy0, qz0, qq0);
      bool c = (da <= Tm0);
      u64 m = __ballot(c);
      if (c){
        float de = dist_exact(P, qx0, qy0, qz0, qq0);
        unsigned pos = cnt0 + mprefix(m);
        if (pos < 128) spair[w][0][pos] = ((u64)f2key(de) << 12) | n;
      }
      cnt0 += (unsigned)__popcll(m);
    }
    {
      float da = DISTA(P, qx1, qy1, qz1, qq1);
      bool c = (da <= Tm1);
      u64 m = __ballot(c);
      if (c){
        float de = dist_exact(P, qx1, qy1, qz1, qq1);
        unsigned pos = cnt1 + mprefix(m);
        if (pos < 128) spair[w][1][pos] = ((u64)f2key(de) << 12) | n;
      }
      cnt1 += (unsigned)__popcll(m);
    }
  }

  const size_t obase = (size_t)q0 * K_;
  if (cnt0 <= 64 && cnt1 <= 64){
    u64 P0 = spair[w][0][l], P1 = spair[w][1][l];
    bsort64_u64x2(P0, P1, l);
    if (l < 32){
      int i0 = (int)(P0 & 0xFFFull);
      int i1 = (int)(P1 & 0xFFFull);
      idxout[obase + l]      = i0;
      idxout[obase + K_ + l] = i1;
      atomicAdd(&multb[i0], 1u);
      atomicAdd(&multb[i1], 1u);
    }
  } else {
    sel_fallback(&spair[w][0][0], cnt0, l, idxout + obase, multb);
    sel_fallback(&spair[w][1][0], cnt1, l, idxout + obase + K_, multb);
  }
}

// ---- conv1u (R23 proven): 65536 unique rows, coalesced pts read, weighted stats ----
__global__ __launch_bounds__(256, 4) void conv1_mfma(const float* __restrict__ pts,
    const unsigned* __restrict__ mult, const unsigned short* __restrict__ wpk,
    const float* __restrict__ bias, unsigned short* __restrict__ Yo,
    float* __restrict__ stats){
  __shared__ float sred[4][128];
  __shared__ uint4 Wl4[512];
  const unsigned short* Wl = (const unsigned short*)Wl4;
  const int t = threadIdx.x, w = t>>6, l = t&63, quad = l>>4, lr = l&15;
  const int Rw = blockIdx.x*128 + w*32;
  Wl4[t] = ((const uint4*)wpk)[t];
  Wl4[256 + t] = ((const uint4*)wpk)[256 + t];
  f32x4 acc[4][2];
  #pragma unroll
  for (int c = 0; c < 4; c++)
    #pragma unroll
    for (int rt = 0; rt < 2; rt++)
      acc[c][rt] = (f32x4){0.f,0.f,0.f,0.f};
  float mf[2];
  mf[0] = (float)mult[Rw + lr];
  mf[1] = (float)mult[Rw + 16 + lr];
  __syncthreads();
  #pragma unroll
  for (int s = 0; s < 2; s++){
    bf16x8 wfs[4];
    #pragma unroll
    for (int c = 0; c < 4; c++)
      wfs[c] = *(const bf16x8*)(Wl + (((c*2+s)<<6) + l)*8);
    #pragma unroll
    for (int rt = 0; rt < 2; rt++){
      const float* pr = pts + (size_t)(Rw + rt*16 + lr)*64;
      float4 v0 = *(const float4*)(pr + s*32 + quad*8);
      float4 v1 = *(const float4*)(pr + s*32 + quad*8 + 4);
      float xs[8] = {v0.x,v0.y,v0.z,v0.w,v1.x,v1.y,v1.z,v1.w};
      bf16x8 xh, xl;
      #pragma unroll
      for (int j = 0; j < 8; j++){ short hh, ll; split1(xs[j], hh, ll); xh[j]=hh; xl[j]=ll; }
      #pragma unroll
      for (int c = 0; c < 4; c++){
        acc[c][rt] = __builtin_amdgcn_mfma_f32_16x16x32_bf16(wfs[c], xh, acc[c][rt], 0,0,0);
        acc[c][rt] = __builtin_amdgcn_mfma_f32_16x16x32_bf16(wfs[c], xl, acc[c][rt], 0,0,0);
      }
    }
  }
  const int rtg0 = Rw >> 4;
  #pragma unroll
  for (int c = 0; c < 4; c++){
    float4 bq = *(const float4*)(bias + c*16 + quad*4);
    float bqa[4] = {bq.x, bq.y, bq.z, bq.w};
    float sv[4] = {0,0,0,0}, qv[4] = {0,0,0,0};
    int kb = c*2 + (quad>>1);
    int sub = (quad&1)*4;
    #pragma unroll
    for (int rt = 0; rt < 2; rt++){
      float y[4];
      #pragma unroll
      for (int r = 0; r < 4; r++){
        y[r] = acc[c][rt][r] + bqa[r];
        sv[r] += mf[rt]*y[r];
        qv[r] += mf[rt]*y[r]*y[r];
      }
      uint2 p;
      p.x = (unsigned)rnb(y[0]) | ((unsigned)rnb(y[1])<<16);
      p.y = (unsigned)rnb(y[2]) | ((unsigned)rnb(y[3])<<16);
      *(uint2*)(Yo + ((((rtg0+rt)*8 + kb)*16 + lr)*8 + sub)) = p;
    }
    float S = hred4_sum(sv, l);
    float Q = hred4_sum(qv, l);
    if ((l & 3) == 0){
      int ch = c*16 + quad*4 + ((l>>3)&1)*2 + ((l>>2)&1);
      sred[w][ch] = S;
      sred[w][64 + ch] = Q;
    }
  }
  __syncthreads();
  if (t < 128){
    float tot = sred[0][t]+sred[1][t]+sred[2][t]+sred[3][t];
    unsafeAtomicAdd(&stats[(blockIdx.x & 7)*512 + t], tot);
  }
}

// ---- conv2u (R23 proven): 65536 unique rows, weighted stats ----
__global__ __launch_bounds__(256, 4) void conv2_mfma(const unsigned short* __restrict__ Yi,
    const unsigned* __restrict__ mult, const unsigned short* __restrict__ wpk,
    const float* __restrict__ bias, const float* __restrict__ gg,
    const float* __restrict__ btv, unsigned short* __restrict__ Yo,
    float* __restrict__ stats){
  __shared__ float sred[4][128];
  __shared__ float sAff[128];
  __shared__ uint4 Wl4[512];
  const unsigned short* Wl = (const unsigned short*)Wl4;
  const int t = threadIdx.x, w = t>>6, l = t&63, quad = l>>4, lr = l&15;
  const int Rw = blockIdx.x*128 + w*32;
  Wl4[t] = ((const uint4*)wpk)[t];
  Wl4[256 + t] = ((const uint4*)wpk)[256 + t];
  if (t < 64){
    const float inv = 1.f/(float)M_;
    float S = 0.f, Q = 0.f;
    #pragma unroll
    for (int r = 0; r < 8; r++){
      S += stats[r*512 + t];
      Q += stats[r*512 + 64 + t];
    }
    float mean = S * inv;
    float var  = Q * inv - mean*mean;
    float a = gg[t] * rsqrtf(var + EPS_);
    sAff[t] = a;
    sAff[64 + t] = btv[t] - mean*a;
  }
  f32x4 acc[4][2];
  #pragma unroll
  for (int c = 0; c < 4; c++)
    #pragma unroll
    for (int rt = 0; rt < 2; rt++)
      acc[c][rt] = (f32x4){0.f,0.f,0.f,0.f};
  float mf[2];
  mf[0] = (float)mult[Rw + lr];
  mf[1] = (float)mult[Rw + 16 + lr];
  const int rtg0 = Rw >> 4;
  uint4 u[2][2];
  #pragma unroll
  for (int s = 0; s < 2; s++)
    #pragma unroll
    for (int rt = 0; rt < 2; rt++)
      u[s][rt] = *(const uint4*)(Yi + (((rtg0+rt)*8 + s*4 + quad)*16 + lr)*8);
  __syncthreads();
  #pragma unroll
  for (int s = 0; s < 2; s++){
    float4 A0 = *(const float4*)(sAff + s*32 + quad*8);
    float4 A1 = *(const float4*)(sAff + s*32 + quad*8 + 4);
    float4 B0 = *(const float4*)(sAff + 64 + s*32 + quad*8);
    float4 B1 = *(const float4*)(sAff + 64 + s*32 + quad*8 + 4);
    float aA[8] = {A0.x,A0.y,A0.z,A0.w,A1.x,A1.y,A1.z,A1.w};
    float aB[8] = {B0.x,B0.y,B0.z,B0.w,B1.x,B1.y,B1.z,B1.w};
    bf16x8 wfs[4];
    #pragma unroll
    for (int c = 0; c < 4; c++)
      wfs[c] = *(const bf16x8*)(Wl + (((c*2+s)<<6) + l)*8);
    #pragma unroll
    for (int rt = 0; rt < 2; rt++){
      unsigned ua[4] = {u[s][rt].x, u[s][rt].y, u[s][rt].z, u[s][rt].w};
      bf16x8 xb;
      #pragma unroll
      for (int j = 0; j < 8; j++){
        unsigned wd = ua[j>>1];
        float yf = __uint_as_float((j&1) ? (wd & 0xFFFF0000u) : (wd << 16));
        float x = fmaxf(0.f, fmaf(yf, aA[j], aB[j]));
        xb[j] = (short)rnb(x);
      }
      #pragma unroll
      for (int c = 0; c < 4; c++)
        acc[c][rt] = __builtin_amdgcn_mfma_f32_16x16x32_bf16(wfs[c], xb, acc[c][rt], 0,0,0);
    }
  }
  #pragma unroll
  for (int c = 0; c < 4; c++){
    float4 bq = *(const float4*)(bias + c*16 + quad*4);
    float bqa[4] = {bq.x, bq.y, bq.z, bq.w};
    float sv[4] = {0,0,0,0}, qv[4] = {0,0,0,0};
    int kb = c*2 + (quad>>1);
    int sub = (quad&1)*4;
    #pragma unroll
    for (int rt = 0; rt < 2; rt++){
      float y[4];
      #pragma unroll
      for (int r = 0; r < 4; r++){
        y[r] = acc[c][rt][r] + bqa[r];
        sv[r] += mf[rt]*y[r];
        qv[r] += mf[rt]*y[r]*y[r];
      }
      uint2 p;
      p.x = (unsigned)rnb(y[0]) | ((unsigned)rnb(y[1])<<16);
      p.y = (unsigned)rnb(y[2]) | ((unsigned)rnb(y[3])<<16);
      *(uint2*)(Yo + ((((rtg0+rt)*8 + kb)*16 + lr)*8 + sub)) = p;
    }
    float S = hred4_sum(sv, l);
    float Q = hred4_sum(qv, l);
    if ((l & 3) == 0){
      int ch = c*16 + quad*4 + ((l>>3)&1)*2 + ((l>>2)&1);
      sred[w][ch] = S;
      sred[w][64 + ch] = Q;
    }
  }
  __syncthreads();
  if (t < 128){
    float tot = sred[0][t]+sred[1][t]+sred[2][t]+sred[3][t];
    unsafeAtomicAdd(&stats[(blockIdx.x & 7)*512 + 128 + t], tot);
  }
}

// ---- conv3u (R23 proven): 65536 unique rows -> zout + weighted stats ----
__global__ __launch_bounds__(256, 3) void conv3_mfma(const unsigned short* __restrict__ Yi,
    const unsigned* __restrict__ mult, const unsigned short* __restrict__ wpk,
    const float* __restrict__ bias, const float* __restrict__ gg,
    const float* __restrict__ btv, float* __restrict__ zout,
    float* __restrict__ stats){
  __shared__ float sred[4][256];
  __shared__ float sAff[128];
  __shared__ uint4 Wl4[1024];
  const unsigned short* Wl = (const unsigned short*)Wl4;
  const int t = threadIdx.x, w = t>>6, l = t&63, quad = l>>4, lr = l&15;
  const int Rw = blockIdx.x*128 + w*32;
  #pragma unroll
  for (int i = 0; i < 4; i++) Wl4[i*256 + t] = ((const uint4*)wpk)[i*256 + t];
  if (t < 64){
    const float inv = 1.f/(float)M_;
    float S = 0.f, Q = 0.f;
    #pragma unroll
    for (int r = 0; r < 8; r++){
      S += stats[r*512 + 128 + t];
      Q += stats[r*512 + 192 + t];
    }
    float mean = S * inv;
    float var  = Q * inv - mean*mean;
    float a = gg[t] * rsqrtf(var + EPS_);
    sAff[t] = a;
    sAff[64 + t] = btv[t] - mean*a;
  }
  f32x4 acc[8][2];
  #pragma unroll
  for (int c = 0; c < 8; c++){
    acc[c][0] = (f32x4){0.f,0.f,0.f,0.f};
    acc[c][1] = (f32x4){0.f,0.f,0.f,0.f};
  }
  float mf[2];
  mf[0] = (float)mult[Rw + lr];
  mf[1] = (float)mult[Rw + 16 + lr];
  const int rtg0 = Rw >> 4;
  uint4 u[2][2];
  #pragma unroll
  for (int s = 0; s < 2; s++)
    #pragma unroll
    for (int rt = 0; rt < 2; rt++)
      u[s][rt] = *(const uint4*)(Yi + (((rtg0+rt)*8 + s*4 + quad)*16 + lr)*8);
  __syncthreads();
  #pragma unroll
  for (int s = 0; s < 2; s++){
    float4 A0 = *(const float4*)(sAff + s*32 + quad*8);
    float4 A1 = *(const float4*)(sAff + s*32 + quad*8 + 4);
    float4 B0 = *(const float4*)(sAff + 64 + s*32 + quad*8);
    float4 B1 = *(const float4*)(sAff + 64 + s*32 + quad*8 + 4);
    float aA[8] = {A0.x,A0.y,A0.z,A0.w,A1.x,A1.y,A1.z,A1.w};
    float aB[8] = {B0.x,B0.y,B0.z,B0.w,B1.x,B1.y,B1.z,B1.w};
    #pragma unroll
    for (int rt = 0; rt < 2; rt++){
      unsigned ua[4] = {u[s][rt].x, u[s][rt].y, u[s][rt].z, u[s][rt].w};
      bf16x8 xb;
      #pragma unroll
      for (int j = 0; j < 8; j++){
        unsigned wd = ua[j>>1];
        float yf = __uint_as_float((j&1) ? (wd & 0xFFFF0000u) : (wd << 16));
        float x = fmaxf(0.f, fmaf(yf, aA[j], aB[j]));
        xb[j] = (short)rnb(x);
      }
      #pragma unroll
      for (int c = 0; c < 8; c++){
        bf16x8 wfc = *(const bf16x8*)(Wl + (((c*2+s)<<6) + l)*8);
        acc[c][rt] = __builtin_amdgcn_mfma_f32_16x16x32_bf16(wfc, xb, acc[c][rt], 0,0,0);
      }
    }
  }
  #pragma unroll
  for (int c = 0; c < 8; c++){
    float4 bq = *(const float4*)(bias + c*16 + quad*4);
    float bqa[4] = {bq.x, bq.y, bq.z, bq.w};
    float sv[4], qv[4];
    #pragma unroll
    for (int rt = 0; rt < 2; rt++){
      float y[4];
      #pragma unroll
      for (int r = 0; r < 4; r++){
        y[r] = acc[c][rt][r] + bqa[r];
        float wy = mf[rt]*y[r];
        if (rt == 0){ sv[r] = wy; qv[r] = wy*y[r]; }
        else        { sv[r] += wy; qv[r] += wy*y[r]; }
      }
      *(float4*)(zout + (size_t)(Rw + rt*16 + lr)*128 + c*16 + quad*4)
          = make_float4(y[0], y[1], y[2], y[3]);
    }
    float S = hred4_sum(sv, l);
    float Q = hred4_sum(qv, l);
    if ((l & 3) == 0){
      int ch = c*16 + quad*4 + ((l>>3)&1)*2 + ((l>>2)&1);
      sred[w][ch] = S;
      sred[w][128 + ch] = Q;
    }
  }
  __syncthreads();
  {
    float tot = sred[0][t]+sred[1][t]+sred[2][t]+sred[3][t];
    unsafeAtomicAdd(&stats[(blockIdx.x & 7)*512 + 256 + t], tot);
  }
}

// ---- maxpool + final fused: per query, max over 32 neighbors' per-point outputs,
// then layer-2 BN affine + relu written directly to out (ymax buffer eliminated) ----
__global__ __launch_bounds__(256, 8) void maxpool_final(const int* __restrict__ idx,
    const float* __restrict__ zout, const float* __restrict__ stats,
    const float* __restrict__ gg, const float* __restrict__ btv,
    float* __restrict__ out){
  __shared__ int sid[4][32];
  __shared__ float sA[128], sB[128];
  const int t = threadIdx.x, w = t>>6, l = t&63;
  const int q = blockIdx.x*4 + w;
  if (l < 32) sid[w][l] = idx[q*32 + l];
  if (t < 128){
    const float inv = 1.f/(float)M_;
    float S = 0.f, Q = 0.f;
    #pragma unroll
    for (int r = 0; r < 8; r++){
      S += stats[r*512 + 256 + t];
      Q += stats[r*512 + 384 + t];
    }
    float mean = S * inv;
    float var  = Q * inv - mean*mean;
    float a = gg[t] * rsqrtf(var + EPS_);
    sA[t] = a;
    sB[t] = btv[t] - mean*a;
  }
  __syncthreads();
  const float* zb = zout + (size_t)(q >> 10) * 4096 * 128;
  float mx = -3.4e38f, my = -3.4e38f;
  #pragma unroll 8
  for (int s = 0; s < 32; s++){
    const float* zp = zb + (size_t)sid[w][s]*128 + l*2;
    float vx = zp[0], vy = zp[1];
    mx = fmaxf(mx, vx);
    my = fmaxf(my, vy);
  }
  const int c0 = l*2, c1 = l*2 + 1;
  out[OUT_FEAT + (size_t)q*128 + c0] = fmaxf(0.f, sA[c0]*mx + sB[c0]);
  out[OUT_FEAT + (size_t)q*128 + c1] = fmaxf(0.f, sA[c1]*my + sB[c1]);
}

extern "C" void kernel_launch(void* const* d_in, const int* in_sizes, int n_in,
                              void* d_out, int out_size, void* d_ws, size_t ws_size,
                              hipStream_t stream) {
  const float* xyz = (const float*)d_in[0];
  const float* nrm = (const float*)d_in[1];
  const float* pts = (const float*)d_in[2];
  const int*   fps = (const int*)d_in[3];
  const float* w0  = (const float*)d_in[4];
  const float* b0  = (const float*)d_in[5];
  const float* g0  = (const float*)d_in[6];
  const float* bt0 = (const float*)d_in[7];
  const float* w1  = (const float*)d_in[8];
  const float* b1  = (const float*)d_in[9];
  const float* g1  = (const float*)d_in[10];
  const float* bt1 = (const float*)d_in[11];
  const float* w2  = (const float*)d_in[12];
  const float* b2  = (const float*)d_in[13];
  const float* g2  = (const float*)d_in[14];
  const float* bt2 = (const float*)d_in[15];
  float* out = (float*)d_out;

  char* ws = (char*)d_ws;
  float* stats = (float*)ws;                                  // 16 KB
  int*   idxb  = (int*)(ws + 20480);                          // 2 MB
  float4* pxyz = (float4*)(ws + 10506240);                    // 1 MB packed xyz
  unsigned short* wpack = (unsigned short*)(ws + 11554816);   // 32 KB
  unsigned* mult = (unsigned*)(ws + 11620352);                // 256 KB multiplicities
  unsigned short* Y1 = (unsigned short*)(ws + 16777216);      // 8 MB (unique rows)
  unsigned short* Y2 = (unsigned short*)(ws + 33554432);      // 8 MB
  float* zout = (float*)(ws + 50331648);                      // 32 MB per-point f32

  prep_kernel<<<656, 256, 0, stream>>>(xyz, nrm, fps, w0, w1, w2, out, pxyz, wpack, stats, mult);
  knn_kernel<<<2048, 256, 0, stream>>>(pxyz, fps, idxb, mult);
  conv1_mfma<<<512, 256, 0, stream>>>(pts, mult, wpack, b0, Y1, stats);
  conv2_mfma<<<512, 256, 0, stream>>>(Y1, mult, wpack + 4096, b1, g0, bt0, Y2, stats);
  conv3_mfma<<<512, 256, 0, stream>>>(Y2, mult, wpack + 8192, b2, g1, bt1, zout, stats);
  maxpool_final<<<4096, 256, 0, stream>>>(idxb, zout, stats, g2, bt2, out);
}